// Round 3
// baseline (458.332 us; speedup 1.0000x reference)
//
#include <hip/hip_runtime.h>

#define N_NODES 50000
#define N_EDGES 1600000
#define F_IN 8
#define HID 1000
#define R_OUT 100
#define CAP 128          // per-node bucket capacity; overflow handled exactly via atomics
#define NCHUNK0 10       // gemv0 split-K chunks (50000/10=5000, /4 ok)

// ======================= helpers =======================

__device__ __forceinline__ unsigned fkey(float f) {
    unsigned b = __float_as_uint(f);
    return (b & 0x80000000u) ? ~b : (b | 0x80000000u);
}
__device__ __forceinline__ float funkey(unsigned k) {
    unsigned b = (k & 0x80000000u) ? (k & 0x7fffffffu) : ~k;
    return __uint_as_float(b);
}

__global__ void init_ws(unsigned* __restrict__ p, int n) {
    int i = blockIdx.x * blockDim.x + threadIdx.x;
    if (i < n) p[i] = 0u;
}

// ======================= fused bucket build =======================
// one pass over edges: rank within dst via atomicAdd; store src into fixed-cap
// bucket row. Overflow edges (deg>CAP, ~never at Poisson(32)) are folded in
// exactly via direct atomics on overflow accumulators.
__global__ void build_kernel(const int* __restrict__ ei,
                             const float* __restrict__ X,
                             const float* __restrict__ wl,     // lin_l_w [8]
                             int* __restrict__ cnt,
                             int* __restrict__ bucket,
                             float* __restrict__ ovf_sum,
                             unsigned* __restrict__ ovf_max) {
    int e = blockIdx.x * blockDim.x + threadIdx.x;
    if (e >= N_EDGES) return;
    int src = ei[e];
    int dst = ei[N_EDGES + e];
    int pos = atomicAdd(&cnt[dst], 1);
    if (pos < CAP) {
        bucket[(size_t)dst * CAP + pos] = src;
    } else {
        const float4* X4 = (const float4*)(X + src * F_IN);
        float4 a = X4[0], b = X4[1];
        float f[8] = {a.x, a.y, a.z, a.w, b.x, b.y, b.z, b.w};
        float d = 0.f;
#pragma unroll
        for (int k = 0; k < 8; ++k) d += f[k] * wl[k];
        atomicAdd(&ovf_sum[dst], d);
        unsigned* mb = ovf_max + (size_t)dst * 8;
#pragma unroll
        for (int k = 0; k < 8; ++k) atomicMax(&mb[k], fkey(f[k]));
    }
}

// ======================= gather + node epilogue =======================
// 16 lanes per node; bucket row is contiguous -> coalesced reads.
__global__ void gather_kernel(const int* __restrict__ bucket,
                              const int* __restrict__ cnt,
                              const float* __restrict__ ovf_sum,
                              const unsigned* __restrict__ ovf_max,
                              const float* __restrict__ X,
                              const float* __restrict__ lin_l_w,
                              const float* __restrict__ lin_l_b,
                              const float* __restrict__ lin_r_w,
                              const float* __restrict__ lin_l1_w,
                              const float* __restrict__ lin_l1_b,
                              const float* __restrict__ lin_r1_w,
                              float* __restrict__ xemb) {
    int t = blockIdx.x * blockDim.x + threadIdx.x;
    int node = t >> 4;
    int sub = t & 15;
    if (node >= N_NODES) return;
    int total = cnt[node];
    int deg = total < CAP ? total : CAP;

    float wl[8];
#pragma unroll
    for (int k = 0; k < 8; ++k) wl[k] = lin_l_w[k];

    float sumdot = 0.f;
    float mx[8];
#pragma unroll
    for (int k = 0; k < 8; ++k) mx[k] = -INFINITY;

    const int* row = bucket + (size_t)node * CAP;
    for (int j = sub; j < deg; j += 16) {
        int src = row[j];
        const float4* X4 = (const float4*)(X + src * F_IN);
        float4 a = X4[0], b = X4[1];
        float f[8] = {a.x, a.y, a.z, a.w, b.x, b.y, b.z, b.w};
        float d = 0.f;
#pragma unroll
        for (int k = 0; k < 8; ++k) d += f[k] * wl[k];
        sumdot += d;
#pragma unroll
        for (int k = 0; k < 8; ++k) mx[k] = fmaxf(mx[k], f[k]);
    }
#pragma unroll
    for (int m = 8; m >= 1; m >>= 1) {
        sumdot += __shfl_xor(sumdot, m, 16);
#pragma unroll
        for (int k = 0; k < 8; ++k) mx[k] = fmaxf(mx[k], __shfl_xor(mx[k], m, 16));
    }
    if (sub == 0) {
        sumdot += ovf_sum[node];                    // zero unless overflow
        if (total > CAP) {                          // merge overflow max (all 8 valid)
            const unsigned* mb = ovf_max + (size_t)node * 8;
#pragma unroll
            for (int k = 0; k < 8; ++k) mx[k] = fmaxf(mx[k], funkey(mb[k]));
        }
        float c = (float)total;
        float mean_dot = sumdot / fmaxf(c, 1.0f);
        const float4* X4 = (const float4*)(X + node * F_IN);
        float4 a = X4[0], b = X4[1];
        float f[8] = {a.x, a.y, a.z, a.w, b.x, b.y, b.z, b.w};
        float dr = 0.f, dr1 = 0.f, dmax = 0.f;
        bool nonempty = (total > 0);
#pragma unroll
        for (int k = 0; k < 8; ++k) {
            float m = nonempty ? mx[k] : 0.0f;
            dmax += m * lin_l1_w[k];
            dr   += f[k] * lin_r_w[k];
            dr1  += f[k] * lin_r1_w[k];
        }
        float hm = fmaxf(mean_dot + lin_l_b[0] + dr, 0.f);
        float hx = fmaxf(dmax + lin_l1_b[0] + dr1, 0.f);
        xemb[node] = hm + hx;
    }
}

// ======================= GEMV =======================

template <int BLOCK, int NCHUNK>
__global__ void gemv_partial(const float* __restrict__ W,
                             const float* __restrict__ x,
                             float* __restrict__ part, int cols) {
    int row = blockIdx.x;
    int c = blockIdx.y;
    int chunk = cols / NCHUNK;
    const float4* W4 = (const float4*)(W + (size_t)row * cols + (size_t)c * chunk);
    const float4* x4 = (const float4*)(x + c * chunk);
    int n4 = chunk >> 2;
    float s = 0.f;
    for (int j = threadIdx.x; j < n4; j += BLOCK) {
        float4 w = W4[j], xx = x4[j];
        s += w.x * xx.x + w.y * xx.y + w.z * xx.z + w.w * xx.w;
    }
#pragma unroll
    for (int off = 32; off > 0; off >>= 1) s += __shfl_down(s, off, 64);
    __shared__ float red[BLOCK / 64];
    int t = threadIdx.x;
    if ((t & 63) == 0) red[t >> 6] = s;
    __syncthreads();
    if (t == 0) {
        float tot = 0.f;
#pragma unroll
        for (int w = 0; w < BLOCK / 64; ++w) tot += red[w];
        part[row * NCHUNK + c] = tot;
    }
}

template <int NCHUNK>
__global__ void gemv_finalize(const float* __restrict__ part,
                              const float* __restrict__ bias,
                              float* __restrict__ y, int rows) {
    int r = blockIdx.x * blockDim.x + threadIdx.x;
    if (r >= rows) return;
    float s = 0.f;
#pragma unroll
    for (int c = 0; c < NCHUNK; ++c) s += part[r * NCHUNK + c];
    y[r] = fmaxf(s + bias[r], 0.f);
}

template <int BLOCK>
__global__ void gemv_relu(const float* __restrict__ W,
                          const float* __restrict__ x,
                          const float* __restrict__ bias,
                          float* __restrict__ y, int cols) {
    int row = blockIdx.x;
    const float4* W4 = (const float4*)(W + (size_t)row * cols);
    const float4* x4 = (const float4*)x;
    int n4 = cols >> 2;
    float s = 0.f;
    for (int j = threadIdx.x; j < n4; j += BLOCK) {
        float4 w = W4[j], xx = x4[j];
        s += w.x * xx.x + w.y * xx.y + w.z * xx.z + w.w * xx.w;
    }
#pragma unroll
    for (int off = 32; off > 0; off >>= 1) s += __shfl_down(s, off, 64);
    __shared__ float red[BLOCK / 64];
    int t = threadIdx.x;
    if ((t & 63) == 0) red[t >> 6] = s;
    __syncthreads();
    if (t == 0) {
        float tot = 0.f;
#pragma unroll
        for (int w = 0; w < BLOCK / 64; ++w) tot += red[w];
        y[row] = fmaxf(tot + bias[row], 0.f);
    }
}

// ======================= fallback (round-1 atomic path) =======================

__global__ void edge_kernel_fb(const int* __restrict__ ei,
                               const float* __restrict__ X,
                               const float* __restrict__ wl,
                               float* __restrict__ sumw,
                               float* __restrict__ cnt,
                               unsigned* __restrict__ maxb) {
    int e = blockIdx.x * blockDim.x + threadIdx.x;
    if (e >= N_EDGES) return;
    int src = ei[e];
    int dst = ei[N_EDGES + e];
    const float4* X4 = (const float4*)(X + src * F_IN);
    float4 a = X4[0], b = X4[1];
    float f[8] = {a.x, a.y, a.z, a.w, b.x, b.y, b.z, b.w};
    float d = 0.f;
#pragma unroll
    for (int k = 0; k < 8; ++k) d += f[k] * wl[k];
    atomicAdd(&sumw[dst], d);
    atomicAdd(&cnt[dst], 1.0f);
    unsigned* mb = maxb + (size_t)dst * 8;
#pragma unroll
    for (int k = 0; k < 8; ++k) atomicMax(&mb[k], fkey(f[k]));
}

__global__ void node_kernel_fb(const float* __restrict__ X,
                               const float* __restrict__ sumw,
                               const float* __restrict__ cnt,
                               const unsigned* __restrict__ maxb,
                               const float* __restrict__ lin_l_b,
                               const float* __restrict__ lin_r_w,
                               const float* __restrict__ lin_l1_w,
                               const float* __restrict__ lin_l1_b,
                               const float* __restrict__ lin_r1_w,
                               float* __restrict__ xout) {
    int i = blockIdx.x * blockDim.x + threadIdx.x;
    if (i >= N_NODES) return;
    float c = cnt[i];
    float mean_dot = sumw[i] / fmaxf(c, 1.0f);
    const float4* X4 = (const float4*)(X + i * F_IN);
    float4 a = X4[0], b = X4[1];
    float f[8] = {a.x, a.y, a.z, a.w, b.x, b.y, b.z, b.w};
    const uint4* M4 = (const uint4*)(maxb + (size_t)i * 8);
    uint4 m0 = M4[0], m1 = M4[1];
    unsigned mk[8] = {m0.x, m0.y, m0.z, m0.w, m1.x, m1.y, m1.z, m1.w};
    float dr = 0.f, dr1 = 0.f, dmax = 0.f;
    bool nonempty = (c > 0.f);
#pragma unroll
    for (int k = 0; k < 8; ++k) {
        float mxv = nonempty ? funkey(mk[k]) : 0.0f;
        dmax += mxv * lin_l1_w[k];
        dr   += f[k] * lin_r_w[k];
        dr1  += f[k] * lin_r1_w[k];
    }
    float hm = fmaxf(mean_dot + lin_l_b[0] + dr, 0.f);
    float hx = fmaxf(dmax + lin_l1_b[0] + dr1, 0.f);
    xout[i] = hm + hx;
}

// ======================= launch =======================

extern "C" void kernel_launch(void* const* d_in, const int* in_sizes, int n_in,
                              void* d_out, int out_size, void* d_ws, size_t ws_size,
                              hipStream_t stream) {
    const float* X        = (const float*)d_in[0];
    const int*   ei       = (const int*)d_in[1];
    const float* lin_l_w  = (const float*)d_in[2];
    const float* lin_l_b  = (const float*)d_in[3];
    const float* lin_r_w  = (const float*)d_in[4];
    const float* lin_l1_w = (const float*)d_in[5];
    const float* lin_l1_b = (const float*)d_in[6];
    const float* lin_r1_w = (const float*)d_in[7];
    const float* W0       = (const float*)d_in[8];
    const float* b0       = (const float*)d_in[9];
    const float* W1       = (const float*)d_in[10];
    const float* b1       = (const float*)d_in[11];
    const float* W2       = (const float*)d_in[12];
    const float* b2       = (const float*)d_in[13];

    float* xemb = (float*)d_out;
    float* out2 = xemb + N_NODES;

    // bucket-path ws layout (4-byte words):
    // [cnt N][ovf_sum N][ovf_max N*8][bucket N*CAP][part0 HID*NCHUNK0][h0 HID][h1 HID]
    const size_t need_words = (size_t)N_NODES * 10 + (size_t)N_NODES * CAP
                              + (size_t)HID * NCHUNK0 + 2 * HID;
    if (ws_size >= need_words * 4) {
        int*      cnt     = (int*)d_ws;                          // [N]
        float*    ovf_sum = (float*)(cnt + N_NODES);             // [N]
        unsigned* ovf_max = (unsigned*)(ovf_sum + N_NODES);      // [N*8]
        int*      bucket  = (int*)(ovf_max + (size_t)N_NODES*8); // [N*CAP]
        float*    part0   = (float*)(bucket + (size_t)N_NODES*CAP); // [HID*NCHUNK0]
        float*    h0      = part0 + HID * NCHUNK0;               // [HID]
        float*    h1      = h0 + HID;                            // [HID]

        int zero_words = N_NODES * 10;  // cnt + ovf_sum + ovf_max (fkey(-inf)>0, key 0 safe)
        hipLaunchKernelGGL(init_ws, dim3((zero_words + 255) / 256), dim3(256), 0, stream,
                           (unsigned*)d_ws, zero_words);
        hipLaunchKernelGGL(build_kernel, dim3((N_EDGES + 255) / 256), dim3(256), 0, stream,
                           ei, X, lin_l_w, cnt, bucket, ovf_sum, ovf_max);
        hipLaunchKernelGGL(gather_kernel, dim3((N_NODES * 16 + 255) / 256), dim3(256), 0, stream,
                           bucket, cnt, ovf_sum, ovf_max, X, lin_l_w, lin_l_b, lin_r_w,
                           lin_l1_w, lin_l1_b, lin_r1_w, xemb);

        hipLaunchKernelGGL((gemv_partial<256, NCHUNK0>), dim3(HID, NCHUNK0), dim3(256), 0, stream,
                           W0, xemb, part0, N_NODES);
        hipLaunchKernelGGL(gemv_finalize<NCHUNK0>, dim3((HID + 255) / 256), dim3(256), 0, stream,
                           part0, b0, h0, HID);
        hipLaunchKernelGGL(gemv_relu<256>, dim3(HID), dim3(256), 0, stream,
                           W1, h0, b1, h1, HID);
        hipLaunchKernelGGL(gemv_relu<256>, dim3(R_OUT), dim3(256), 0, stream,
                           W2, h1, b2, out2, HID);
    } else {
        // fallback: round-1 atomic path (needs ~2 MB)
        float*    sumw = (float*)d_ws;
        float*    cntf = sumw + N_NODES;
        unsigned* maxb = (unsigned*)(cntf + N_NODES);
        float*    h0   = (float*)(maxb + (size_t)N_NODES * 8);
        float*    h1   = h0 + HID;

        int zero_words = N_NODES * 10;
        hipLaunchKernelGGL(init_ws, dim3((zero_words + 255) / 256), dim3(256), 0, stream,
                           (unsigned*)d_ws, zero_words);
        hipLaunchKernelGGL(edge_kernel_fb, dim3((N_EDGES + 255) / 256), dim3(256), 0, stream,
                           ei, X, lin_l_w, sumw, cntf, maxb);
        hipLaunchKernelGGL(node_kernel_fb, dim3((N_NODES + 255) / 256), dim3(256), 0, stream,
                           X, sumw, cntf, maxb, lin_l_b, lin_r_w, lin_l1_w, lin_l1_b,
                           lin_r1_w, xemb);
        hipLaunchKernelGGL(gemv_relu<256>, dim3(HID), dim3(256), 0, stream,
                           W0, xemb, b0, h0, N_NODES);
        hipLaunchKernelGGL(gemv_relu<256>, dim3(HID), dim3(256), 0, stream,
                           W1, h0, b1, h1, HID);
        hipLaunchKernelGGL(gemv_relu<256>, dim3(R_OUT), dim3(256), 0, stream,
                           W2, h1, b2, out2, HID);
    }
}

// Round 4
// 426.555 us; speedup vs baseline: 1.0745x; 1.0745x over previous
//
#include <hip/hip_runtime.h>

#define N_NODES 50000
#define N_EDGES 1600000
#define F_IN 8
#define HID 1000
#define R_OUT 100

#define NGRP 8                 // append groups (aligned with blockIdx%8 ~ XCD)
#define BSHIFT 6               // bucket = dst >> 6
#define NPB 64                 // nodes per bucket
#define NB 782                 // ceil(50000/64)
#define CAP_B 448              // capacity per (group,bucket); mean 256, +12 sigma
#define NCHUNK0 25             // gemv0 split-K chunks (50000/25=2000, /4 ok)

// ======================= helpers =======================

__device__ __forceinline__ unsigned fkey(float f) {
    unsigned b = __float_as_uint(f);
    return (b & 0x80000000u) ? ~b : (b | 0x80000000u);
}
__device__ __forceinline__ float funkey(unsigned k) {
    unsigned b = (k & 0x80000000u) ? (k & 0x7fffffffu) : ~k;
    return __uint_as_float(b);
}

__global__ void init_ws(unsigned* __restrict__ p, int n) {
    int i = blockIdx.x * blockDim.x + threadIdx.x;
    if (i < n) p[i] = 0u;
}

// ======================= pass 1: bin edges =======================
// entry = src | (dst_low << 16); 4B appends into (group,bucket) lists.
__global__ void bin_kernel(const int* __restrict__ ei,
                           const float* __restrict__ X,
                           const float* __restrict__ wl,
                           int* __restrict__ bcnt,          // [NGRP*NB]
                           unsigned* __restrict__ binned,   // [NGRP*NB*CAP_B]
                           int* __restrict__ ovf_cnt,
                           float* __restrict__ ovf_sum,
                           unsigned* __restrict__ ovf_max) {
    int e = blockIdx.x * blockDim.x + threadIdx.x;
    if (e >= N_EDGES) return;
    int src = ei[e];
    int dst = ei[N_EDGES + e];
    int b = dst >> BSHIFT;
    int g = blockIdx.x & (NGRP - 1);
    int slot = g * NB + b;
    int pos = atomicAdd(&bcnt[slot], 1);
    if (pos < CAP_B) {
        binned[(size_t)slot * CAP_B + pos] = (unsigned)src | ((unsigned)(dst & (NPB - 1)) << 16);
    } else {
        // exact overflow path (statistically never taken)
        const float4* X4 = (const float4*)(X + src * F_IN);
        float4 a = X4[0], bb = X4[1];
        float f[8] = {a.x, a.y, a.z, a.w, bb.x, bb.y, bb.z, bb.w};
        float d = 0.f;
#pragma unroll
        for (int k = 0; k < 8; ++k) d += f[k] * wl[k];
        atomicAdd(&ovf_cnt[dst], 1);
        atomicAdd(&ovf_sum[dst], d);
        unsigned* mb = ovf_max + (size_t)dst * 8;
#pragma unroll
        for (int k = 0; k < 8; ++k) atomicMax(&mb[k], fkey(f[k]));
    }
}

// ======================= pass 2: aggregate + node epilogue =======================
// one block per bucket; LDS accumulators for 64 nodes; fused epilogue -> xemb.
__global__ void agg_kernel(const int* __restrict__ bcnt,
                           const unsigned* __restrict__ binned,
                           const int* __restrict__ ovf_cnt,
                           const float* __restrict__ ovf_sum,
                           const unsigned* __restrict__ ovf_max,
                           const float* __restrict__ X,
                           const float* __restrict__ lin_l_w,
                           const float* __restrict__ lin_l_b,
                           const float* __restrict__ lin_r_w,
                           const float* __restrict__ lin_l1_w,
                           const float* __restrict__ lin_l1_b,
                           const float* __restrict__ lin_r1_w,
                           float* __restrict__ xemb) {
    __shared__ unsigned lds[NPB * 10];   // [0,64) sumdot(f32) | [64,128) cnt | [128+k*64] max keys
    float* sdot = (float*)lds;
    unsigned* scnt = lds + NPB;
    unsigned* smax = lds + 2 * NPB;      // smax[k*NPB + n]

    int b = blockIdx.x;
    int tid = threadIdx.x;

    for (int i = tid; i < NPB * 10; i += 256) lds[i] = 0u;   // key 0 < fkey(anything)
    __syncthreads();

    float wl[8];
#pragma unroll
    for (int k = 0; k < 8; ++k) wl[k] = lin_l_w[k];

    for (int g = 0; g < NGRP; ++g) {
        int slot = g * NB + b;
        int n = bcnt[slot];
        if (n > CAP_B) n = CAP_B;
        const unsigned* list = binned + (size_t)slot * CAP_B;
        for (int j = tid; j < n; j += 256) {
            unsigned p = list[j];
            int src = p & 0xFFFF;
            int dlow = p >> 16;
            const float4* X4 = (const float4*)(X + src * F_IN);
            float4 a = X4[0], bb = X4[1];
            float f[8] = {a.x, a.y, a.z, a.w, bb.x, bb.y, bb.z, bb.w};
            float d = 0.f;
#pragma unroll
            for (int k = 0; k < 8; ++k) d += f[k] * wl[k];
            atomicAdd(&sdot[dlow], d);
            atomicAdd(&scnt[dlow], 1u);
#pragma unroll
            for (int k = 0; k < 8; ++k) atomicMax(&smax[k * NPB + dlow], fkey(f[k]));
        }
    }
    __syncthreads();

    if (tid < NPB) {
        int node = b * NPB + tid;
        if (node < N_NODES) {
            int total = (int)scnt[tid] + ovf_cnt[node];
            float sumdot = sdot[tid] + ovf_sum[node];
            float mx[8];
#pragma unroll
            for (int k = 0; k < 8; ++k) mx[k] = funkey(smax[k * NPB + tid]);
            if (ovf_cnt[node] > 0) {
                const unsigned* mb = ovf_max + (size_t)node * 8;
#pragma unroll
                for (int k = 0; k < 8; ++k) mx[k] = fmaxf(mx[k], funkey(mb[k]));
            }
            float c = (float)total;
            float mean_dot = sumdot / fmaxf(c, 1.0f);
            const float4* X4 = (const float4*)(X + node * F_IN);
            float4 a = X4[0], bb = X4[1];
            float f[8] = {a.x, a.y, a.z, a.w, bb.x, bb.y, bb.z, bb.w};
            float dr = 0.f, dr1 = 0.f, dmax = 0.f;
            bool nonempty = (total > 0);
#pragma unroll
            for (int k = 0; k < 8; ++k) {
                float m = nonempty ? mx[k] : 0.0f;
                dmax += m * lin_l1_w[k];
                dr   += f[k] * lin_r_w[k];
                dr1  += f[k] * lin_r1_w[k];
            }
            float hm = fmaxf(mean_dot + lin_l_b[0] + dr, 0.f);
            float hx = fmaxf(dmax + lin_l1_b[0] + dr1, 0.f);
            xemb[node] = hm + hx;
        }
    }
}

// ======================= GEMV =======================

template <int BLOCK, int NCHUNK>
__global__ void gemv_partial(const float* __restrict__ W,
                             const float* __restrict__ x,
                             float* __restrict__ part, int cols) {
    int row = blockIdx.x;
    int c = blockIdx.y;
    int chunk = cols / NCHUNK;
    const float4* W4 = (const float4*)(W + (size_t)row * cols + (size_t)c * chunk);
    const float4* x4 = (const float4*)(x + c * chunk);
    int n4 = chunk >> 2;
    float s = 0.f;
    for (int j = threadIdx.x; j < n4; j += BLOCK) {
        float4 w = W4[j], xx = x4[j];
        s += w.x * xx.x + w.y * xx.y + w.z * xx.z + w.w * xx.w;
    }
#pragma unroll
    for (int off = 32; off > 0; off >>= 1) s += __shfl_down(s, off, 64);
    __shared__ float red[BLOCK / 64];
    int t = threadIdx.x;
    if ((t & 63) == 0) red[t >> 6] = s;
    __syncthreads();
    if (t == 0) {
        float tot = 0.f;
#pragma unroll
        for (int w = 0; w < BLOCK / 64; ++w) tot += red[w];
        part[row * NCHUNK + c] = tot;
    }
}

template <int NCHUNK>
__global__ void gemv_finalize(const float* __restrict__ part,
                              const float* __restrict__ bias,
                              float* __restrict__ y, int rows) {
    int r = blockIdx.x * blockDim.x + threadIdx.x;
    if (r >= rows) return;
    float s = 0.f;
#pragma unroll
    for (int c = 0; c < NCHUNK; ++c) s += part[r * NCHUNK + c];
    y[r] = fmaxf(s + bias[r], 0.f);
}

template <int BLOCK>
__global__ void gemv_relu(const float* __restrict__ W,
                          const float* __restrict__ x,
                          const float* __restrict__ bias,
                          float* __restrict__ y, int cols) {
    int row = blockIdx.x;
    const float4* W4 = (const float4*)(W + (size_t)row * cols);
    const float4* x4 = (const float4*)x;
    int n4 = cols >> 2;
    float s = 0.f;
    for (int j = threadIdx.x; j < n4; j += BLOCK) {
        float4 w = W4[j], xx = x4[j];
        s += w.x * xx.x + w.y * xx.y + w.z * xx.z + w.w * xx.w;
    }
#pragma unroll
    for (int off = 32; off > 0; off >>= 1) s += __shfl_down(s, off, 64);
    __shared__ float red[BLOCK / 64];
    int t = threadIdx.x;
    if ((t & 63) == 0) red[t >> 6] = s;
    __syncthreads();
    if (t == 0) {
        float tot = 0.f;
#pragma unroll
        for (int w = 0; w < BLOCK / 64; ++w) tot += red[w];
        y[row] = fmaxf(tot + bias[row], 0.f);
    }
}

// ======================= fallback (round-1 atomic path) =======================

__global__ void edge_kernel_fb(const int* __restrict__ ei,
                               const float* __restrict__ X,
                               const float* __restrict__ wl,
                               float* __restrict__ sumw,
                               float* __restrict__ cnt,
                               unsigned* __restrict__ maxb) {
    int e = blockIdx.x * blockDim.x + threadIdx.x;
    if (e >= N_EDGES) return;
    int src = ei[e];
    int dst = ei[N_EDGES + e];
    const float4* X4 = (const float4*)(X + src * F_IN);
    float4 a = X4[0], b = X4[1];
    float f[8] = {a.x, a.y, a.z, a.w, b.x, b.y, b.z, b.w};
    float d = 0.f;
#pragma unroll
    for (int k = 0; k < 8; ++k) d += f[k] * wl[k];
    atomicAdd(&sumw[dst], d);
    atomicAdd(&cnt[dst], 1.0f);
    unsigned* mb = maxb + (size_t)dst * 8;
#pragma unroll
    for (int k = 0; k < 8; ++k) atomicMax(&mb[k], fkey(f[k]));
}

__global__ void node_kernel_fb(const float* __restrict__ X,
                               const float* __restrict__ sumw,
                               const float* __restrict__ cnt,
                               const unsigned* __restrict__ maxb,
                               const float* __restrict__ lin_l_b,
                               const float* __restrict__ lin_r_w,
                               const float* __restrict__ lin_l1_w,
                               const float* __restrict__ lin_l1_b,
                               const float* __restrict__ lin_r1_w,
                               float* __restrict__ xout) {
    int i = blockIdx.x * blockDim.x + threadIdx.x;
    if (i >= N_NODES) return;
    float c = cnt[i];
    float mean_dot = sumw[i] / fmaxf(c, 1.0f);
    const float4* X4 = (const float4*)(X + i * F_IN);
    float4 a = X4[0], b = X4[1];
    float f[8] = {a.x, a.y, a.z, a.w, b.x, b.y, b.z, b.w};
    const uint4* M4 = (const uint4*)(maxb + (size_t)i * 8);
    uint4 m0 = M4[0], m1 = M4[1];
    unsigned mk[8] = {m0.x, m0.y, m0.z, m0.w, m1.x, m1.y, m1.z, m1.w};
    float dr = 0.f, dr1 = 0.f, dmax = 0.f;
    bool nonempty = (c > 0.f);
#pragma unroll
    for (int k = 0; k < 8; ++k) {
        float mxv = nonempty ? funkey(mk[k]) : 0.0f;
        dmax += mxv * lin_l1_w[k];
        dr   += f[k] * lin_r_w[k];
        dr1  += f[k] * lin_r1_w[k];
    }
    float hm = fmaxf(mean_dot + lin_l_b[0] + dr, 0.f);
    float hx = fmaxf(dmax + lin_l1_b[0] + dr1, 0.f);
    xout[i] = hm + hx;
}

// ======================= launch =======================

extern "C" void kernel_launch(void* const* d_in, const int* in_sizes, int n_in,
                              void* d_out, int out_size, void* d_ws, size_t ws_size,
                              hipStream_t stream) {
    const float* X        = (const float*)d_in[0];
    const int*   ei       = (const int*)d_in[1];
    const float* lin_l_w  = (const float*)d_in[2];
    const float* lin_l_b  = (const float*)d_in[3];
    const float* lin_r_w  = (const float*)d_in[4];
    const float* lin_l1_w = (const float*)d_in[5];
    const float* lin_l1_b = (const float*)d_in[6];
    const float* lin_r1_w = (const float*)d_in[7];
    const float* W0       = (const float*)d_in[8];
    const float* b0       = (const float*)d_in[9];
    const float* W1       = (const float*)d_in[10];
    const float* b1       = (const float*)d_in[11];
    const float* W2       = (const float*)d_in[12];
    const float* b2       = (const float*)d_in[13];

    float* xemb = (float*)d_out;
    float* out2 = xemb + N_NODES;

    // ws layout (words): zeroed region first: [bcnt NGRP*NB][ovf_cnt N][ovf_sum N][ovf_max N*8]
    // then: [binned NGRP*NB*CAP_B][part0 HID*NCHUNK0][h0 HID][h1 HID]
    const size_t zero_words = (size_t)NGRP * NB + (size_t)N_NODES * 10;
    const size_t need_words = zero_words + (size_t)NGRP * NB * CAP_B
                              + (size_t)HID * NCHUNK0 + 2 * HID;
    if (ws_size >= need_words * 4) {
        int*      bcnt    = (int*)d_ws;                            // [NGRP*NB]
        int*      ovf_cnt = bcnt + NGRP * NB;                      // [N]
        float*    ovf_sum = (float*)(ovf_cnt + N_NODES);           // [N]
        unsigned* ovf_max = (unsigned*)(ovf_sum + N_NODES);        // [N*8]
        unsigned* binned  = ovf_max + (size_t)N_NODES * 8;         // [NGRP*NB*CAP_B]
        float*    part0   = (float*)(binned + (size_t)NGRP * NB * CAP_B);
        float*    h0      = part0 + HID * NCHUNK0;
        float*    h1      = h0 + HID;

        hipLaunchKernelGGL(init_ws, dim3(((int)zero_words + 255) / 256), dim3(256), 0, stream,
                           (unsigned*)d_ws, (int)zero_words);
        hipLaunchKernelGGL(bin_kernel, dim3((N_EDGES + 255) / 256), dim3(256), 0, stream,
                           ei, X, lin_l_w, bcnt, binned, ovf_cnt, ovf_sum, ovf_max);
        hipLaunchKernelGGL(agg_kernel, dim3(NB), dim3(256), 0, stream,
                           bcnt, binned, ovf_cnt, ovf_sum, ovf_max, X,
                           lin_l_w, lin_l_b, lin_r_w, lin_l1_w, lin_l1_b, lin_r1_w, xemb);

        hipLaunchKernelGGL((gemv_partial<256, NCHUNK0>), dim3(HID, NCHUNK0), dim3(256), 0, stream,
                           W0, xemb, part0, N_NODES);
        hipLaunchKernelGGL(gemv_finalize<NCHUNK0>, dim3((HID + 255) / 256), dim3(256), 0, stream,
                           part0, b0, h0, HID);
        hipLaunchKernelGGL(gemv_relu<256>, dim3(HID), dim3(256), 0, stream,
                           W1, h0, b1, h1, HID);
        hipLaunchKernelGGL(gemv_relu<256>, dim3(R_OUT), dim3(256), 0, stream,
                           W2, h1, b2, out2, HID);
    } else {
        float*    sumw = (float*)d_ws;
        float*    cntf = sumw + N_NODES;
        unsigned* maxb = (unsigned*)(cntf + N_NODES);
        float*    h0   = (float*)(maxb + (size_t)N_NODES * 8);
        float*    h1   = h0 + HID;

        int zw = N_NODES * 10;
        hipLaunchKernelGGL(init_ws, dim3((zw + 255) / 256), dim3(256), 0, stream,
                           (unsigned*)d_ws, zw);
        hipLaunchKernelGGL(edge_kernel_fb, dim3((N_EDGES + 255) / 256), dim3(256), 0, stream,
                           ei, X, lin_l_w, sumw, cntf, maxb);
        hipLaunchKernelGGL(node_kernel_fb, dim3((N_NODES + 255) / 256), dim3(256), 0, stream,
                           X, sumw, cntf, maxb, lin_l_b, lin_r_w, lin_l1_w, lin_l1_b,
                           lin_r1_w, xemb);
        hipLaunchKernelGGL(gemv_relu<256>, dim3(HID), dim3(256), 0, stream,
                           W0, xemb, b0, h0, N_NODES);
        hipLaunchKernelGGL(gemv_relu<256>, dim3(HID), dim3(256), 0, stream,
                           W1, h0, b1, h1, HID);
        hipLaunchKernelGGL(gemv_relu<256>, dim3(R_OUT), dim3(256), 0, stream,
                           W2, h1, b2, out2, HID);
    }
}

// Round 5
// 380.010 us; speedup vs baseline: 1.2061x; 1.1225x over previous
//
#include <hip/hip_runtime.h>

#define N_NODES 50000
#define N_EDGES 1600000
#define F_IN 8
#define HID 1000
#define R_OUT 100

#define BSHIFT 6               // bucket = dst >> 6
#define NPB 64                 // nodes per bucket
#define NB 782                 // ceil(50000/64)
#define CAP_B 2400             // per-bucket capacity; mean 2046, +8 sigma; 2400%16==0
#define CHUNK 4096             // edges per bin block
#define NBIN_BLOCKS ((N_EDGES + CHUNK - 1) / CHUNK)   // 391
#define NCHUNK0 25             // gemv0 split-K chunks (50000/25=2000, /4 ok)

// ======================= helpers =======================

__device__ __forceinline__ unsigned fkey(float f) {
    unsigned b = __float_as_uint(f);
    return (b & 0x80000000u) ? ~b : (b | 0x80000000u);
}
__device__ __forceinline__ float funkey(unsigned k) {
    unsigned b = (k & 0x80000000u) ? (k & 0x7fffffffu) : ~k;
    return __uint_as_float(b);
}

__global__ void init_ws(unsigned* __restrict__ p, int n) {
    int i = blockIdx.x * blockDim.x + threadIdx.x;
    if (i < n) p[i] = 0u;
}

// ======================= pass 1: LDS-staged binning =======================
// Per block: LDS histogram over buckets -> one global cursor reservation per
// (block,bucket) -> ranked scatter into contiguous bucket lists.
// Global atomics: ~NB per block (~300K total) instead of 1 per edge (1.6M).
__global__ void bin_kernel(const int* __restrict__ ei,
                           const float* __restrict__ X,
                           const float* __restrict__ wl,
                           int* __restrict__ cursor,        // [NB]
                           unsigned* __restrict__ binned,   // [NB*CAP_B]
                           int* __restrict__ ovf_cnt,
                           float* __restrict__ ovf_sum,
                           unsigned* __restrict__ ovf_max) {
    __shared__ int hist[NB];
    __shared__ int pos[NB];
    __shared__ int base[NB];
    int tid = threadIdx.x;
    int e0 = blockIdx.x * CHUNK;
    int e1 = e0 + CHUNK;
    if (e1 > N_EDGES) e1 = N_EDGES;

    for (int i = tid; i < NB; i += 256) { hist[i] = 0; pos[i] = 0; }
    __syncthreads();

    // phase A: histogram of this chunk's dst buckets
    for (int e = e0 + tid; e < e1; e += 256) {
        int dst = ei[N_EDGES + e];
        atomicAdd(&hist[dst >> BSHIFT], 1);
    }
    __syncthreads();

    // phase B: reserve contiguous ranges in global bucket lists
    for (int b = tid; b < NB; b += 256) {
        int h = hist[b];
        base[b] = (h > 0) ? atomicAdd(&cursor[b], h) : 0;
    }
    __syncthreads();

    // phase C: ranked scatter (packed entry: src | dstlow<<16)
    for (int e = e0 + tid; e < e1; e += 256) {
        int src = ei[e];
        int dst = ei[N_EDGES + e];
        int b = dst >> BSHIFT;
        int p = atomicAdd(&pos[b], 1);
        int gp = base[b] + p;
        if (gp < CAP_B) {
            binned[(size_t)b * CAP_B + gp] =
                (unsigned)src | ((unsigned)(dst & (NPB - 1)) << 16);
        } else {
            // exact overflow path (statistically never taken)
            const float4* X4 = (const float4*)(X + src * F_IN);
            float4 a = X4[0], bb = X4[1];
            float f[8] = {a.x, a.y, a.z, a.w, bb.x, bb.y, bb.z, bb.w};
            float d = 0.f;
#pragma unroll
            for (int k = 0; k < 8; ++k) d += f[k] * wl[k];
            atomicAdd(&ovf_cnt[dst], 1);
            atomicAdd(&ovf_sum[dst], d);
            unsigned* mb = ovf_max + (size_t)dst * 8;
#pragma unroll
            for (int k = 0; k < 8; ++k) atomicMax(&mb[k], fkey(f[k]));
        }
    }
}

// ======================= pass 2: aggregate + node epilogue =======================
// one block per bucket; LDS accumulators for 64 nodes; fused epilogue -> xemb.
__global__ void agg_kernel(const int* __restrict__ cursor,
                           const unsigned* __restrict__ binned,
                           const int* __restrict__ ovf_cnt,
                           const float* __restrict__ ovf_sum,
                           const unsigned* __restrict__ ovf_max,
                           const float* __restrict__ X,
                           const float* __restrict__ lin_l_w,
                           const float* __restrict__ lin_l_b,
                           const float* __restrict__ lin_r_w,
                           const float* __restrict__ lin_l1_w,
                           const float* __restrict__ lin_l1_b,
                           const float* __restrict__ lin_r1_w,
                           float* __restrict__ xemb) {
    __shared__ unsigned lds[NPB * 10];   // sumdot f32 | cnt | 8x max keys
    float* sdot = (float*)lds;
    unsigned* scnt = lds + NPB;
    unsigned* smax = lds + 2 * NPB;      // smax[k*NPB + n]

    int b = blockIdx.x;
    int tid = threadIdx.x;

    for (int i = tid; i < NPB * 10; i += 256) lds[i] = 0u;   // key 0 < fkey(anything)
    __syncthreads();

    float wl[8];
#pragma unroll
    for (int k = 0; k < 8; ++k) wl[k] = lin_l_w[k];

    int n = cursor[b];
    if (n > CAP_B) n = CAP_B;
    const unsigned* list = binned + (size_t)b * CAP_B;
    for (int j = tid; j < n; j += 256) {
        unsigned p = list[j];
        int src = p & 0xFFFF;
        int dlow = p >> 16;
        const float4* X4 = (const float4*)(X + src * F_IN);
        float4 a = X4[0], bb = X4[1];
        float f[8] = {a.x, a.y, a.z, a.w, bb.x, bb.y, bb.z, bb.w};
        float d = 0.f;
#pragma unroll
        for (int k = 0; k < 8; ++k) d += f[k] * wl[k];
        atomicAdd(&sdot[dlow], d);
        atomicAdd(&scnt[dlow], 1u);
#pragma unroll
        for (int k = 0; k < 8; ++k) atomicMax(&smax[k * NPB + dlow], fkey(f[k]));
    }
    __syncthreads();

    if (tid < NPB) {
        int node = b * NPB + tid;
        if (node < N_NODES) {
            int oc = ovf_cnt[node];
            int total = (int)scnt[tid] + oc;
            float sumdot = sdot[tid] + ovf_sum[node];
            float mx[8];
#pragma unroll
            for (int k = 0; k < 8; ++k) mx[k] = funkey(smax[k * NPB + tid]);
            if (oc > 0) {
                const unsigned* mb = ovf_max + (size_t)node * 8;
#pragma unroll
                for (int k = 0; k < 8; ++k) mx[k] = fmaxf(mx[k], funkey(mb[k]));
            }
            float c = (float)total;
            float mean_dot = sumdot / fmaxf(c, 1.0f);
            const float4* X4 = (const float4*)(X + node * F_IN);
            float4 a = X4[0], bb = X4[1];
            float f[8] = {a.x, a.y, a.z, a.w, bb.x, bb.y, bb.z, bb.w};
            float dr = 0.f, dr1 = 0.f, dmax = 0.f;
            bool nonempty = (total > 0);
#pragma unroll
            for (int k = 0; k < 8; ++k) {
                float m = nonempty ? mx[k] : 0.0f;
                dmax += m * lin_l1_w[k];
                dr   += f[k] * lin_r_w[k];
                dr1  += f[k] * lin_r1_w[k];
            }
            float hm = fmaxf(mean_dot + lin_l_b[0] + dr, 0.f);
            float hx = fmaxf(dmax + lin_l1_b[0] + dr1, 0.f);
            xemb[node] = hm + hx;
        }
    }
}

// ======================= GEMV =======================

template <int BLOCK, int NCHUNK>
__global__ void gemv_partial(const float* __restrict__ W,
                             const float* __restrict__ x,
                             float* __restrict__ part, int cols) {
    int row = blockIdx.x;
    int c = blockIdx.y;
    int chunk = cols / NCHUNK;
    const float4* W4 = (const float4*)(W + (size_t)row * cols + (size_t)c * chunk);
    const float4* x4 = (const float4*)(x + c * chunk);
    int n4 = chunk >> 2;
    float s = 0.f;
    for (int j = threadIdx.x; j < n4; j += BLOCK) {
        float4 w = W4[j], xx = x4[j];
        s += w.x * xx.x + w.y * xx.y + w.z * xx.z + w.w * xx.w;
    }
#pragma unroll
    for (int off = 32; off > 0; off >>= 1) s += __shfl_down(s, off, 64);
    __shared__ float red[BLOCK / 64];
    int t = threadIdx.x;
    if ((t & 63) == 0) red[t >> 6] = s;
    __syncthreads();
    if (t == 0) {
        float tot = 0.f;
#pragma unroll
        for (int w = 0; w < BLOCK / 64; ++w) tot += red[w];
        part[row * NCHUNK + c] = tot;
    }
}

template <int NCHUNK>
__global__ void gemv_finalize(const float* __restrict__ part,
                              const float* __restrict__ bias,
                              float* __restrict__ y, int rows) {
    int r = blockIdx.x * blockDim.x + threadIdx.x;
    if (r >= rows) return;
    float s = 0.f;
#pragma unroll
    for (int c = 0; c < NCHUNK; ++c) s += part[r * NCHUNK + c];
    y[r] = fmaxf(s + bias[r], 0.f);
}

template <int BLOCK>
__global__ void gemv_relu(const float* __restrict__ W,
                          const float* __restrict__ x,
                          const float* __restrict__ bias,
                          float* __restrict__ y, int cols) {
    int row = blockIdx.x;
    const float4* W4 = (const float4*)(W + (size_t)row * cols);
    const float4* x4 = (const float4*)x;
    int n4 = cols >> 2;
    float s = 0.f;
    for (int j = threadIdx.x; j < n4; j += BLOCK) {
        float4 w = W4[j], xx = x4[j];
        s += w.x * xx.x + w.y * xx.y + w.z * xx.z + w.w * xx.w;
    }
#pragma unroll
    for (int off = 32; off > 0; off >>= 1) s += __shfl_down(s, off, 64);
    __shared__ float red[BLOCK / 64];
    int t = threadIdx.x;
    if ((t & 63) == 0) red[t >> 6] = s;
    __syncthreads();
    if (t == 0) {
        float tot = 0.f;
#pragma unroll
        for (int w = 0; w < BLOCK / 64; ++w) tot += red[w];
        y[row] = fmaxf(tot + bias[row], 0.f);
    }
}

// ======================= fallback (round-1 atomic path) =======================

__global__ void edge_kernel_fb(const int* __restrict__ ei,
                               const float* __restrict__ X,
                               const float* __restrict__ wl,
                               float* __restrict__ sumw,
                               float* __restrict__ cnt,
                               unsigned* __restrict__ maxb) {
    int e = blockIdx.x * blockDim.x + threadIdx.x;
    if (e >= N_EDGES) return;
    int src = ei[e];
    int dst = ei[N_EDGES + e];
    const float4* X4 = (const float4*)(X + src * F_IN);
    float4 a = X4[0], b = X4[1];
    float f[8] = {a.x, a.y, a.z, a.w, b.x, b.y, b.z, b.w};
    float d = 0.f;
#pragma unroll
    for (int k = 0; k < 8; ++k) d += f[k] * wl[k];
    atomicAdd(&sumw[dst], d);
    atomicAdd(&cnt[dst], 1.0f);
    unsigned* mb = maxb + (size_t)dst * 8;
#pragma unroll
    for (int k = 0; k < 8; ++k) atomicMax(&mb[k], fkey(f[k]));
}

__global__ void node_kernel_fb(const float* __restrict__ X,
                               const float* __restrict__ sumw,
                               const float* __restrict__ cnt,
                               const unsigned* __restrict__ maxb,
                               const float* __restrict__ lin_l_b,
                               const float* __restrict__ lin_r_w,
                               const float* __restrict__ lin_l1_w,
                               const float* __restrict__ lin_l1_b,
                               const float* __restrict__ lin_r1_w,
                               float* __restrict__ xout) {
    int i = blockIdx.x * blockDim.x + threadIdx.x;
    if (i >= N_NODES) return;
    float c = cnt[i];
    float mean_dot = sumw[i] / fmaxf(c, 1.0f);
    const float4* X4 = (const float4*)(X + i * F_IN);
    float4 a = X4[0], b = X4[1];
    float f[8] = {a.x, a.y, a.z, a.w, b.x, b.y, b.z, b.w};
    const uint4* M4 = (const uint4*)(maxb + (size_t)i * 8);
    uint4 m0 = M4[0], m1 = M4[1];
    unsigned mk[8] = {m0.x, m0.y, m0.z, m0.w, m1.x, m1.y, m1.z, m1.w};
    float dr = 0.f, dr1 = 0.f, dmax = 0.f;
    bool nonempty = (c > 0.f);
#pragma unroll
    for (int k = 0; k < 8; ++k) {
        float mxv = nonempty ? funkey(mk[k]) : 0.0f;
        dmax += mxv * lin_l1_w[k];
        dr   += f[k] * lin_r_w[k];
        dr1  += f[k] * lin_r1_w[k];
    }
    float hm = fmaxf(mean_dot + lin_l_b[0] + dr, 0.f);
    float hx = fmaxf(dmax + lin_l1_b[0] + dr1, 0.f);
    xout[i] = hm + hx;
}

// ======================= launch =======================

extern "C" void kernel_launch(void* const* d_in, const int* in_sizes, int n_in,
                              void* d_out, int out_size, void* d_ws, size_t ws_size,
                              hipStream_t stream) {
    const float* X        = (const float*)d_in[0];
    const int*   ei       = (const int*)d_in[1];
    const float* lin_l_w  = (const float*)d_in[2];
    const float* lin_l_b  = (const float*)d_in[3];
    const float* lin_r_w  = (const float*)d_in[4];
    const float* lin_l1_w = (const float*)d_in[5];
    const float* lin_l1_b = (const float*)d_in[6];
    const float* lin_r1_w = (const float*)d_in[7];
    const float* W0       = (const float*)d_in[8];
    const float* b0       = (const float*)d_in[9];
    const float* W1       = (const float*)d_in[10];
    const float* b1       = (const float*)d_in[11];
    const float* W2       = (const float*)d_in[12];
    const float* b2       = (const float*)d_in[13];

    float* xemb = (float*)d_out;
    float* out2 = xemb + N_NODES;

    // ws layout (words): zeroed first: [cursor NB][ovf_cnt N][ovf_sum N][ovf_max N*8]
    // then: [binned NB*CAP_B][part0 HID*NCHUNK0][h0 HID][h1 HID]
    const size_t zero_words = (size_t)NB + (size_t)N_NODES * 10;
    const size_t need_words = zero_words + (size_t)NB * CAP_B
                              + (size_t)HID * NCHUNK0 + 2 * HID;
    if (ws_size >= need_words * 4) {
        int*      cursor  = (int*)d_ws;                            // [NB]
        int*      ovf_cnt = cursor + NB;                           // [N]
        float*    ovf_sum = (float*)(ovf_cnt + N_NODES);           // [N]
        unsigned* ovf_max = (unsigned*)(ovf_sum + N_NODES);        // [N*8]
        unsigned* binned  = ovf_max + (size_t)N_NODES * 8;         // [NB*CAP_B]
        float*    part0   = (float*)(binned + (size_t)NB * CAP_B); // [HID*NCHUNK0]
        float*    h0      = part0 + HID * NCHUNK0;                 // [HID]
        float*    h1      = h0 + HID;                              // [HID]

        hipLaunchKernelGGL(init_ws, dim3(((int)zero_words + 255) / 256), dim3(256), 0, stream,
                           (unsigned*)d_ws, (int)zero_words);
        hipLaunchKernelGGL(bin_kernel, dim3(NBIN_BLOCKS), dim3(256), 0, stream,
                           ei, X, lin_l_w, cursor, binned, ovf_cnt, ovf_sum, ovf_max);
        hipLaunchKernelGGL(agg_kernel, dim3(NB), dim3(256), 0, stream,
                           cursor, binned, ovf_cnt, ovf_sum, ovf_max, X,
                           lin_l_w, lin_l_b, lin_r_w, lin_l1_w, lin_l1_b, lin_r1_w, xemb);

        hipLaunchKernelGGL((gemv_partial<256, NCHUNK0>), dim3(HID, NCHUNK0), dim3(256), 0, stream,
                           W0, xemb, part0, N_NODES);
        hipLaunchKernelGGL(gemv_finalize<NCHUNK0>, dim3((HID + 255) / 256), dim3(256), 0, stream,
                           part0, b0, h0, HID);
        hipLaunchKernelGGL(gemv_relu<256>, dim3(HID), dim3(256), 0, stream,
                           W1, h0, b1, h1, HID);
        hipLaunchKernelGGL(gemv_relu<256>, dim3(R_OUT), dim3(256), 0, stream,
                           W2, h1, b2, out2, HID);
    } else {
        float*    sumw = (float*)d_ws;
        float*    cntf = sumw + N_NODES;
        unsigned* maxb = (unsigned*)(cntf + N_NODES);
        float*    h0   = (float*)(maxb + (size_t)N_NODES * 8);
        float*    h1   = h0 + HID;

        int zw = N_NODES * 10;
        hipLaunchKernelGGL(init_ws, dim3((zw + 255) / 256), dim3(256), 0, stream,
                           (unsigned*)d_ws, zw);
        hipLaunchKernelGGL(edge_kernel_fb, dim3((N_EDGES + 255) / 256), dim3(256), 0, stream,
                           ei, X, lin_l_w, sumw, cntf, maxb);
        hipLaunchKernelGGL(node_kernel_fb, dim3((N_NODES + 255) / 256), dim3(256), 0, stream,
                           X, sumw, cntf, maxb, lin_l_b, lin_r_w, lin_l1_w, lin_l1_b,
                           lin_r1_w, xemb);
        hipLaunchKernelGGL(gemv_relu<256>, dim3(HID), dim3(256), 0, stream,
                           W0, xemb, b0, h0, N_NODES);
        hipLaunchKernelGGL(gemv_relu<256>, dim3(HID), dim3(256), 0, stream,
                           W1, h0, b1, h1, HID);
        hipLaunchKernelGGL(gemv_relu<256>, dim3(R_OUT), dim3(256), 0, stream,
                           W2, h1, b2, out2, HID);
    }
}

// Round 6
// 359.555 us; speedup vs baseline: 1.2747x; 1.0569x over previous
//
#include <hip/hip_runtime.h>

#define N_NODES 50000
#define N_EDGES 1600000
#define F_IN 8
#define HID 1000
#define R_OUT 100

#define BSHIFT 6               // bucket = dst >> 6
#define NPB 64                 // nodes per bucket
#define NB 782                 // ceil(50000/64)
#define CAP_B 2400             // per-bucket capacity; mean 2046, +8 sigma
#define CHUNK 4096             // edges per bin block
#define NBIN_BLOCKS ((N_EDGES + CHUNK - 1) / CHUNK)   // 391
#define NCHUNK0 25             // gemv0 split-K chunks (50000/25=2000, /4 ok)

// ======================= helpers =======================

__device__ __forceinline__ unsigned fkey(float f) {
    unsigned b = __float_as_uint(f);
    return (b & 0x80000000u) ? ~b : (b | 0x80000000u);
}
__device__ __forceinline__ float funkey(unsigned k) {
    unsigned b = (k & 0x80000000u) ? (k & 0x7fffffffu) : ~k;
    return __uint_as_float(b);
}

__global__ void init_ws(unsigned* __restrict__ p, int n) {
    int i = blockIdx.x * blockDim.x + threadIdx.x;
    if (i < n) p[i] = 0u;
}

// ======================= pass 1: LDS-staged binning =======================
// Phase A reads ei ONCE, staging packed entries + bucket ids in LDS while
// building the per-bucket histogram. Phase B reserves global ranges (1 atomic
// per (block,bucket) ~= 300K total). Phase C scatters from LDS.
__global__ void bin_kernel(const int* __restrict__ ei,
                           const float* __restrict__ X,
                           const float* __restrict__ wl,
                           int* __restrict__ cursor,        // [NB]
                           unsigned* __restrict__ binned,   // [NB*CAP_B]
                           int* __restrict__ ovf_cnt,
                           float* __restrict__ ovf_sum,
                           unsigned* __restrict__ ovf_max) {
    __shared__ unsigned sEntry[CHUNK];     // 16 KB
    __shared__ unsigned short sBucket[CHUNK]; // 8 KB
    __shared__ int hist[NB];
    __shared__ int pos[NB];
    __shared__ int base[NB];
    int tid = threadIdx.x;
    int e0 = blockIdx.x * CHUNK;
    int e1 = e0 + CHUNK;
    if (e1 > N_EDGES) e1 = N_EDGES;
    int ne = e1 - e0;

    for (int i = tid; i < NB; i += 256) { hist[i] = 0; pos[i] = 0; }
    __syncthreads();

    // phase A: single read of ei; stage + histogram
    for (int j = tid; j < ne; j += 256) {
        int src = ei[e0 + j];
        int dst = ei[N_EDGES + e0 + j];
        int b = dst >> BSHIFT;
        sEntry[j] = (unsigned)src | ((unsigned)(dst & (NPB - 1)) << 16);
        sBucket[j] = (unsigned short)b;
        atomicAdd(&hist[b], 1);
    }
    __syncthreads();

    // phase B: reserve contiguous ranges in global bucket lists
    for (int b = tid; b < NB; b += 256) {
        int h = hist[b];
        base[b] = (h > 0) ? atomicAdd(&cursor[b], h) : 0;
    }
    __syncthreads();

    // phase C: ranked scatter from LDS
    for (int j = tid; j < ne; j += 256) {
        unsigned entry = sEntry[j];
        int b = sBucket[j];
        int p = atomicAdd(&pos[b], 1);
        int gp = base[b] + p;
        if (gp < CAP_B) {
            binned[(size_t)b * CAP_B + gp] = entry;
        } else {
            // exact overflow path (statistically never taken)
            int src = entry & 0xFFFF;
            int dst = b * NPB + (int)(entry >> 16);
            const float4* X4 = (const float4*)(X + src * F_IN);
            float4 a = X4[0], bb = X4[1];
            float f[8] = {a.x, a.y, a.z, a.w, bb.x, bb.y, bb.z, bb.w};
            float d = 0.f;
#pragma unroll
            for (int k = 0; k < 8; ++k) d += f[k] * wl[k];
            atomicAdd(&ovf_cnt[dst], 1);
            atomicAdd(&ovf_sum[dst], d);
            unsigned* mb = ovf_max + (size_t)dst * 8;
#pragma unroll
            for (int k = 0; k < 8; ++k) atomicMax(&mb[k], fkey(f[k]));
        }
    }
}

// ======================= pass 2: sort-then-reduce aggregation =======================
// One block per bucket. Counting-sort entries by dst-low in LDS (2 LDS atomics
// per edge), then 4 threads per node accumulate in REGISTERS (no atomics),
// merge via shuffles, fused epilogue -> xemb.
__global__ void agg_kernel(const int* __restrict__ cursor,
                           const unsigned* __restrict__ binned,
                           const int* __restrict__ ovf_cnt,
                           const float* __restrict__ ovf_sum,
                           const unsigned* __restrict__ ovf_max,
                           const float* __restrict__ X,
                           const float* __restrict__ lin_l_w,
                           const float* __restrict__ lin_l_b,
                           const float* __restrict__ lin_r_w,
                           const float* __restrict__ lin_l1_w,
                           const float* __restrict__ lin_l1_b,
                           const float* __restrict__ lin_r1_w,
                           float* __restrict__ xemb) {
    __shared__ unsigned sEntry[CAP_B];    // 9.6 KB
    __shared__ unsigned sSorted[CAP_B];   // 9.6 KB
    __shared__ int sCnt[NPB];
    __shared__ int sOff[NPB];
    __shared__ int sPos[NPB];

    int b = blockIdx.x;
    int tid = threadIdx.x;
    int n = cursor[b];
    if (n > CAP_B) n = CAP_B;

    if (tid < NPB) { sCnt[tid] = 0; sPos[tid] = 0; }
    __syncthreads();

    // load + count
    for (int j = tid; j < n; j += 256) {
        unsigned e = binned[(size_t)b * CAP_B + j];
        sEntry[j] = e;
        atomicAdd(&sCnt[e >> 16], 1);
    }
    __syncthreads();

    // exclusive prefix over 64 counters (serial on t0: ~64 iters, negligible)
    if (tid == 0) {
        int run = 0;
#pragma unroll
        for (int i = 0; i < NPB; ++i) { sOff[i] = run; run += sCnt[i]; }
    }
    __syncthreads();

    // scatter to sorted order
    for (int j = tid; j < n; j += 256) {
        unsigned e = sEntry[j];
        int d = e >> 16;
        int p = atomicAdd(&sPos[d], 1);
        sSorted[sOff[d] + p] = e;
    }
    __syncthreads();

    // register accumulation: 4 threads per node
    int nl = tid >> 2;       // node-local [0,64)
    int r = tid & 3;
    int beg = sOff[nl];
    int cnt = sCnt[nl];

    float wl[8];
#pragma unroll
    for (int k = 0; k < 8; ++k) wl[k] = lin_l_w[k];

    float sumdot = 0.f;
    float mx[8];
#pragma unroll
    for (int k = 0; k < 8; ++k) mx[k] = -INFINITY;

    for (int j = beg + r; j < beg + cnt; j += 4) {
        int src = sSorted[j] & 0xFFFF;
        const float4* X4 = (const float4*)(X + src * F_IN);
        float4 a = X4[0], bb = X4[1];
        float f[8] = {a.x, a.y, a.z, a.w, bb.x, bb.y, bb.z, bb.w};
        float d = 0.f;
#pragma unroll
        for (int k = 0; k < 8; ++k) d += f[k] * wl[k];
        sumdot += d;
#pragma unroll
        for (int k = 0; k < 8; ++k) mx[k] = fmaxf(mx[k], f[k]);
    }
    // merge the 4 lanes of this node (contiguous lanes within one wave)
#pragma unroll
    for (int m = 1; m <= 2; m <<= 1) {
        sumdot += __shfl_xor(sumdot, m, 4);
#pragma unroll
        for (int k = 0; k < 8; ++k) mx[k] = fmaxf(mx[k], __shfl_xor(mx[k], m, 4));
    }

    if (r == 0) {
        int node = b * NPB + nl;
        if (node < N_NODES) {
            int oc = ovf_cnt[node];
            int total = cnt + oc;
            float sd = sumdot + ovf_sum[node];
            if (oc > 0) {
                const unsigned* mb = ovf_max + (size_t)node * 8;
#pragma unroll
                for (int k = 0; k < 8; ++k) mx[k] = fmaxf(mx[k], funkey(mb[k]));
            }
            float c = (float)total;
            float mean_dot = sd / fmaxf(c, 1.0f);
            const float4* X4 = (const float4*)(X + node * F_IN);
            float4 a = X4[0], bb = X4[1];
            float f[8] = {a.x, a.y, a.z, a.w, bb.x, bb.y, bb.z, bb.w};
            float dr = 0.f, dr1 = 0.f, dmax = 0.f;
            bool nonempty = (total > 0);
#pragma unroll
            for (int k = 0; k < 8; ++k) {
                float m = nonempty ? mx[k] : 0.0f;
                dmax += m * lin_l1_w[k];
                dr   += f[k] * lin_r_w[k];
                dr1  += f[k] * lin_r1_w[k];
            }
            float hm = fmaxf(mean_dot + lin_l_b[0] + dr, 0.f);
            float hx = fmaxf(dmax + lin_l1_b[0] + dr1, 0.f);
            xemb[node] = hm + hx;
        }
    }
}

// ======================= GEMV =======================

template <int BLOCK, int NCHUNK>
__global__ void gemv_partial(const float* __restrict__ W,
                             const float* __restrict__ x,
                             float* __restrict__ part, int cols) {
    int row = blockIdx.x;
    int c = blockIdx.y;
    int chunk = cols / NCHUNK;
    const float4* W4 = (const float4*)(W + (size_t)row * cols + (size_t)c * chunk);
    const float4* x4 = (const float4*)(x + c * chunk);
    int n4 = chunk >> 2;
    float s = 0.f;
    for (int j = threadIdx.x; j < n4; j += BLOCK) {
        float4 w = W4[j], xx = x4[j];
        s += w.x * xx.x + w.y * xx.y + w.z * xx.z + w.w * xx.w;
    }
#pragma unroll
    for (int off = 32; off > 0; off >>= 1) s += __shfl_down(s, off, 64);
    __shared__ float red[BLOCK / 64];
    int t = threadIdx.x;
    if ((t & 63) == 0) red[t >> 6] = s;
    __syncthreads();
    if (t == 0) {
        float tot = 0.f;
#pragma unroll
        for (int w = 0; w < BLOCK / 64; ++w) tot += red[w];
        part[row * NCHUNK + c] = tot;
    }
}

template <int NCHUNK>
__global__ void gemv_finalize(const float* __restrict__ part,
                              const float* __restrict__ bias,
                              float* __restrict__ y, int rows) {
    int r = blockIdx.x * blockDim.x + threadIdx.x;
    if (r >= rows) return;
    float s = 0.f;
#pragma unroll
    for (int c = 0; c < NCHUNK; ++c) s += part[r * NCHUNK + c];
    y[r] = fmaxf(s + bias[r], 0.f);
}

template <int BLOCK>
__global__ void gemv_relu(const float* __restrict__ W,
                          const float* __restrict__ x,
                          const float* __restrict__ bias,
                          float* __restrict__ y, int cols) {
    int row = blockIdx.x;
    const float4* W4 = (const float4*)(W + (size_t)row * cols);
    const float4* x4 = (const float4*)x;
    int n4 = cols >> 2;
    float s = 0.f;
    for (int j = threadIdx.x; j < n4; j += BLOCK) {
        float4 w = W4[j], xx = x4[j];
        s += w.x * xx.x + w.y * xx.y + w.z * xx.z + w.w * xx.w;
    }
#pragma unroll
    for (int off = 32; off > 0; off >>= 1) s += __shfl_down(s, off, 64);
    __shared__ float red[BLOCK / 64];
    int t = threadIdx.x;
    if ((t & 63) == 0) red[t >> 6] = s;
    __syncthreads();
    if (t == 0) {
        float tot = 0.f;
#pragma unroll
        for (int w = 0; w < BLOCK / 64; ++w) tot += red[w];
        y[row] = fmaxf(tot + bias[row], 0.f);
    }
}

// ======================= fallback (round-1 atomic path) =======================

__global__ void edge_kernel_fb(const int* __restrict__ ei,
                               const float* __restrict__ X,
                               const float* __restrict__ wl,
                               float* __restrict__ sumw,
                               float* __restrict__ cnt,
                               unsigned* __restrict__ maxb) {
    int e = blockIdx.x * blockDim.x + threadIdx.x;
    if (e >= N_EDGES) return;
    int src = ei[e];
    int dst = ei[N_EDGES + e];
    const float4* X4 = (const float4*)(X + src * F_IN);
    float4 a = X4[0], b = X4[1];
    float f[8] = {a.x, a.y, a.z, a.w, b.x, b.y, b.z, b.w};
    float d = 0.f;
#pragma unroll
    for (int k = 0; k < 8; ++k) d += f[k] * wl[k];
    atomicAdd(&sumw[dst], d);
    atomicAdd(&cnt[dst], 1.0f);
    unsigned* mb = maxb + (size_t)dst * 8;
#pragma unroll
    for (int k = 0; k < 8; ++k) atomicMax(&mb[k], fkey(f[k]));
}

__global__ void node_kernel_fb(const float* __restrict__ X,
                               const float* __restrict__ sumw,
                               const float* __restrict__ cnt,
                               const unsigned* __restrict__ maxb,
                               const float* __restrict__ lin_l_b,
                               const float* __restrict__ lin_r_w,
                               const float* __restrict__ lin_l1_w,
                               const float* __restrict__ lin_l1_b,
                               const float* __restrict__ lin_r1_w,
                               float* __restrict__ xout) {
    int i = blockIdx.x * blockDim.x + threadIdx.x;
    if (i >= N_NODES) return;
    float c = cnt[i];
    float mean_dot = sumw[i] / fmaxf(c, 1.0f);
    const float4* X4 = (const float4*)(X + i * F_IN);
    float4 a = X4[0], b = X4[1];
    float f[8] = {a.x, a.y, a.z, a.w, b.x, b.y, b.z, b.w};
    const uint4* M4 = (const uint4*)(maxb + (size_t)i * 8);
    uint4 m0 = M4[0], m1 = M4[1];
    unsigned mk[8] = {m0.x, m0.y, m0.z, m0.w, m1.x, m1.y, m1.z, m1.w};
    float dr = 0.f, dr1 = 0.f, dmax = 0.f;
    bool nonempty = (c > 0.f);
#pragma unroll
    for (int k = 0; k < 8; ++k) {
        float mxv = nonempty ? funkey(mk[k]) : 0.0f;
        dmax += mxv * lin_l1_w[k];
        dr   += f[k] * lin_r_w[k];
        dr1  += f[k] * lin_r1_w[k];
    }
    float hm = fmaxf(mean_dot + lin_l_b[0] + dr, 0.f);
    float hx = fmaxf(dmax + lin_l1_b[0] + dr1, 0.f);
    xout[i] = hm + hx;
}

// ======================= launch =======================

extern "C" void kernel_launch(void* const* d_in, const int* in_sizes, int n_in,
                              void* d_out, int out_size, void* d_ws, size_t ws_size,
                              hipStream_t stream) {
    const float* X        = (const float*)d_in[0];
    const int*   ei       = (const int*)d_in[1];
    const float* lin_l_w  = (const float*)d_in[2];
    const float* lin_l_b  = (const float*)d_in[3];
    const float* lin_r_w  = (const float*)d_in[4];
    const float* lin_l1_w = (const float*)d_in[5];
    const float* lin_l1_b = (const float*)d_in[6];
    const float* lin_r1_w = (const float*)d_in[7];
    const float* W0       = (const float*)d_in[8];
    const float* b0       = (const float*)d_in[9];
    const float* W1       = (const float*)d_in[10];
    const float* b1       = (const float*)d_in[11];
    const float* W2       = (const float*)d_in[12];
    const float* b2       = (const float*)d_in[13];

    float* xemb = (float*)d_out;
    float* out2 = xemb + N_NODES;

    // ws layout (words): zeroed first: [cursor NB][ovf_cnt N][ovf_sum N][ovf_max N*8]
    // then: [binned NB*CAP_B][part0 HID*NCHUNK0][h0 HID][h1 HID]
    const size_t zero_words = (size_t)NB + (size_t)N_NODES * 10;
    const size_t need_words = zero_words + (size_t)NB * CAP_B
                              + (size_t)HID * NCHUNK0 + 2 * HID;
    if (ws_size >= need_words * 4) {
        int*      cursor  = (int*)d_ws;                            // [NB]
        int*      ovf_cnt = cursor + NB;                           // [N]
        float*    ovf_sum = (float*)(ovf_cnt + N_NODES);           // [N]
        unsigned* ovf_max = (unsigned*)(ovf_sum + N_NODES);        // [N*8]
        unsigned* binned  = ovf_max + (size_t)N_NODES * 8;         // [NB*CAP_B]
        float*    part0   = (float*)(binned + (size_t)NB * CAP_B); // [HID*NCHUNK0]
        float*    h0      = part0 + HID * NCHUNK0;                 // [HID]
        float*    h1      = h0 + HID;                              // [HID]

        hipLaunchKernelGGL(init_ws, dim3(((int)zero_words + 255) / 256), dim3(256), 0, stream,
                           (unsigned*)d_ws, (int)zero_words);
        hipLaunchKernelGGL(bin_kernel, dim3(NBIN_BLOCKS), dim3(256), 0, stream,
                           ei, X, lin_l_w, cursor, binned, ovf_cnt, ovf_sum, ovf_max);
        hipLaunchKernelGGL(agg_kernel, dim3(NB), dim3(256), 0, stream,
                           cursor, binned, ovf_cnt, ovf_sum, ovf_max, X,
                           lin_l_w, lin_l_b, lin_r_w, lin_l1_w, lin_l1_b, lin_r1_w, xemb);

        hipLaunchKernelGGL((gemv_partial<256, NCHUNK0>), dim3(HID, NCHUNK0), dim3(256), 0, stream,
                           W0, xemb, part0, N_NODES);
        hipLaunchKernelGGL(gemv_finalize<NCHUNK0>, dim3((HID + 255) / 256), dim3(256), 0, stream,
                           part0, b0, h0, HID);
        hipLaunchKernelGGL(gemv_relu<256>, dim3(HID), dim3(256), 0, stream,
                           W1, h0, b1, h1, HID);
        hipLaunchKernelGGL(gemv_relu<256>, dim3(R_OUT), dim3(256), 0, stream,
                           W2, h1, b2, out2, HID);
    } else {
        float*    sumw = (float*)d_ws;
        float*    cntf = sumw + N_NODES;
        unsigned* maxb = (unsigned*)(cntf + N_NODES);
        float*    h0   = (float*)(maxb + (size_t)N_NODES * 8);
        float*    h1   = h0 + HID;

        int zw = N_NODES * 10;
        hipLaunchKernelGGL(init_ws, dim3((zw + 255) / 256), dim3(256), 0, stream,
                           (unsigned*)d_ws, zw);
        hipLaunchKernelGGL(edge_kernel_fb, dim3((N_EDGES + 255) / 256), dim3(256), 0, stream,
                           ei, X, lin_l_w, sumw, cntf, maxb);
        hipLaunchKernelGGL(node_kernel_fb, dim3((N_NODES + 255) / 256), dim3(256), 0, stream,
                           X, sumw, cntf, maxb, lin_l_b, lin_r_w, lin_l1_w, lin_l1_b,
                           lin_r1_w, xemb);
        hipLaunchKernelGGL(gemv_relu<256>, dim3(HID), dim3(256), 0, stream,
                           W0, xemb, b0, h0, N_NODES);
        hipLaunchKernelGGL(gemv_relu<256>, dim3(HID), dim3(256), 0, stream,
                           W1, h0, b1, h1, HID);
        hipLaunchKernelGGL(gemv_relu<256>, dim3(R_OUT), dim3(256), 0, stream,
                           W2, h1, b2, out2, HID);
    }
}

// Round 7
// 358.091 us; speedup vs baseline: 1.2799x; 1.0041x over previous
//
#include <hip/hip_runtime.h>

#define N_NODES 50000
#define N_EDGES 1600000
#define F_IN 8
#define HID 1000
#define R_OUT 100

#define BSHIFT 7               // bucket = dst >> 7
#define NPB 128                // nodes per bucket
#define NB 391                 // ceil(50000/128)
#define CAP_B 4608             // per-bucket capacity; mean 4096, +8 sigma
#define CHUNK 4096             // edges per bin block
#define NBIN_BLOCKS ((N_EDGES + CHUNK - 1) / CHUNK)   // 391
#define NCHUNK0 25             // gemv0 split-K chunks (50000/25=2000, /4 ok)

// ======================= helpers =======================

__device__ __forceinline__ unsigned fkey(float f) {
    unsigned b = __float_as_uint(f);
    return (b & 0x80000000u) ? ~b : (b | 0x80000000u);
}
__device__ __forceinline__ float funkey(unsigned k) {
    unsigned b = (k & 0x80000000u) ? (k & 0x7fffffffu) : ~k;
    return __uint_as_float(b);
}

// zero the cursor/ovf region and seed h0 with b0 (gemv0 accumulates into it)
__global__ void init_kernel(unsigned* __restrict__ p, int nzero,
                            const float* __restrict__ b0, float* __restrict__ h0) {
    int i = blockIdx.x * blockDim.x + threadIdx.x;
    if (i < nzero) p[i] = 0u;
    if (i < HID) h0[i] = b0[i];
}

// ======================= pass 1: LDS-staged binning =======================
// Phase A reads ei once, staging packed entries + bucket ids in LDS while
// building the per-bucket histogram. Phase B reserves global ranges (1 atomic
// per (block,bucket) ~= 153K total). Phase C scatters from LDS.
__global__ void bin_kernel(const int* __restrict__ ei,
                           const float* __restrict__ X,
                           const float* __restrict__ wl,
                           int* __restrict__ cursor,        // [NB]
                           unsigned* __restrict__ binned,   // [NB*CAP_B]
                           int* __restrict__ ovf_cnt,
                           float* __restrict__ ovf_sum,
                           unsigned* __restrict__ ovf_max) {
    __shared__ unsigned sEntry[CHUNK];        // 16 KB
    __shared__ unsigned short sBucket[CHUNK]; // 8 KB
    __shared__ int hist[NB];
    __shared__ int pos[NB];
    __shared__ int base[NB];
    int tid = threadIdx.x;
    int e0 = blockIdx.x * CHUNK;
    int e1 = e0 + CHUNK;
    if (e1 > N_EDGES) e1 = N_EDGES;
    int ne = e1 - e0;

    for (int i = tid; i < NB; i += 256) { hist[i] = 0; pos[i] = 0; }
    __syncthreads();

    // phase A: single read of ei; stage + histogram
    for (int j = tid; j < ne; j += 256) {
        int src = ei[e0 + j];
        int dst = ei[N_EDGES + e0 + j];
        int b = dst >> BSHIFT;
        sEntry[j] = (unsigned)src | ((unsigned)(dst & (NPB - 1)) << 16);
        sBucket[j] = (unsigned short)b;
        atomicAdd(&hist[b], 1);
    }
    __syncthreads();

    // phase B: reserve contiguous ranges in global bucket lists
    for (int b = tid; b < NB; b += 256) {
        int h = hist[b];
        base[b] = (h > 0) ? atomicAdd(&cursor[b], h) : 0;
    }
    __syncthreads();

    // phase C: ranked scatter from LDS
    for (int j = tid; j < ne; j += 256) {
        unsigned entry = sEntry[j];
        int b = sBucket[j];
        int p = atomicAdd(&pos[b], 1);
        int gp = base[b] + p;
        if (gp < CAP_B) {
            binned[(size_t)b * CAP_B + gp] = entry;
        } else {
            // exact overflow path (statistically never taken)
            int src = entry & 0xFFFF;
            int dst = b * NPB + (int)(entry >> 16);
            const float4* X4 = (const float4*)(X + src * F_IN);
            float4 a = X4[0], bb = X4[1];
            float f[8] = {a.x, a.y, a.z, a.w, bb.x, bb.y, bb.z, bb.w};
            float d = 0.f;
#pragma unroll
            for (int k = 0; k < 8; ++k) d += f[k] * wl[k];
            atomicAdd(&ovf_cnt[dst], 1);
            atomicAdd(&ovf_sum[dst], d);
            unsigned* mb = ovf_max + (size_t)dst * 8;
#pragma unroll
            for (int k = 0; k < 8; ++k) atomicMax(&mb[k], fkey(f[k]));
        }
    }
}

// ======================= pass 2: sort-then-reduce aggregation =======================
// One 512-thread block per bucket (128 nodes). Counting-sort entries by
// dst-low in LDS, then 4 threads per node accumulate in registers, merge via
// shuffles, fused epilogue -> xemb.
__global__ void agg_kernel(const int* __restrict__ cursor,
                           const unsigned* __restrict__ binned,
                           const int* __restrict__ ovf_cnt,
                           const float* __restrict__ ovf_sum,
                           const unsigned* __restrict__ ovf_max,
                           const float* __restrict__ X,
                           const float* __restrict__ lin_l_w,
                           const float* __restrict__ lin_l_b,
                           const float* __restrict__ lin_r_w,
                           const float* __restrict__ lin_l1_w,
                           const float* __restrict__ lin_l1_b,
                           const float* __restrict__ lin_r1_w,
                           float* __restrict__ xemb) {
    __shared__ unsigned sEntry[CAP_B];    // 18.4 KB
    __shared__ unsigned sSorted[CAP_B];   // 18.4 KB
    __shared__ int sCnt[NPB];
    __shared__ int sOff[NPB];
    __shared__ int sPos[NPB];

    int b = blockIdx.x;
    int tid = threadIdx.x;
    int n = cursor[b];
    if (n > CAP_B) n = CAP_B;

    if (tid < NPB) { sCnt[tid] = 0; sPos[tid] = 0; }
    __syncthreads();

    // load + count
    for (int j = tid; j < n; j += 512) {
        unsigned e = binned[(size_t)b * CAP_B + j];
        sEntry[j] = e;
        atomicAdd(&sCnt[e >> 16], 1);
    }
    __syncthreads();

    // exclusive prefix over 128 counters (serial on t0, negligible)
    if (tid == 0) {
        int run = 0;
#pragma unroll
        for (int i = 0; i < NPB; ++i) { sOff[i] = run; run += sCnt[i]; }
    }
    __syncthreads();

    // scatter to sorted order
    for (int j = tid; j < n; j += 512) {
        unsigned e = sEntry[j];
        int d = e >> 16;
        int p = atomicAdd(&sPos[d], 1);
        sSorted[sOff[d] + p] = e;
    }
    __syncthreads();

    // register accumulation: 4 threads per node
    int nl = tid >> 2;       // node-local [0,128)
    int r = tid & 3;
    int beg = sOff[nl];
    int cnt = sCnt[nl];

    float wl[8];
#pragma unroll
    for (int k = 0; k < 8; ++k) wl[k] = lin_l_w[k];

    float sumdot = 0.f;
    float mx[8];
#pragma unroll
    for (int k = 0; k < 8; ++k) mx[k] = -INFINITY;

    for (int j = beg + r; j < beg + cnt; j += 4) {
        int src = sSorted[j] & 0xFFFF;
        const float4* X4 = (const float4*)(X + src * F_IN);
        float4 a = X4[0], bb = X4[1];
        float f[8] = {a.x, a.y, a.z, a.w, bb.x, bb.y, bb.z, bb.w};
        float d = 0.f;
#pragma unroll
        for (int k = 0; k < 8; ++k) d += f[k] * wl[k];
        sumdot += d;
#pragma unroll
        for (int k = 0; k < 8; ++k) mx[k] = fmaxf(mx[k], f[k]);
    }
    // merge the 4 lanes of this node (contiguous lanes within one wave)
#pragma unroll
    for (int m = 1; m <= 2; m <<= 1) {
        sumdot += __shfl_xor(sumdot, m, 4);
#pragma unroll
        for (int k = 0; k < 8; ++k) mx[k] = fmaxf(mx[k], __shfl_xor(mx[k], m, 4));
    }

    if (r == 0) {
        int node = b * NPB + nl;
        if (node < N_NODES) {
            int oc = ovf_cnt[node];
            int total = cnt + oc;
            float sd = sumdot + ovf_sum[node];
            if (oc > 0) {
                const unsigned* mb = ovf_max + (size_t)node * 8;
#pragma unroll
                for (int k = 0; k < 8; ++k) mx[k] = fmaxf(mx[k], funkey(mb[k]));
            }
            float c = (float)total;
            float mean_dot = sd / fmaxf(c, 1.0f);
            const float4* X4 = (const float4*)(X + node * F_IN);
            float4 a = X4[0], bb = X4[1];
            float f[8] = {a.x, a.y, a.z, a.w, bb.x, bb.y, bb.z, bb.w};
            float dr = 0.f, dr1 = 0.f, dmax = 0.f;
            bool nonempty = (total > 0);
#pragma unroll
            for (int k = 0; k < 8; ++k) {
                float m = nonempty ? mx[k] : 0.0f;
                dmax += m * lin_l1_w[k];
                dr   += f[k] * lin_r_w[k];
                dr1  += f[k] * lin_r1_w[k];
            }
            float hm = fmaxf(mean_dot + lin_l_b[0] + dr, 0.f);
            float hx = fmaxf(dmax + lin_l1_b[0] + dr1, 0.f);
            xemb[node] = hm + hx;
        }
    }
}

// ======================= GEMV =======================

// split-K gemv accumulating atomically into y (pre-seeded with bias).
// grid: (NCHUNK, rows) -> consecutive blocks read consecutive chunks (sequential HBM).
template <int BLOCK, int NCHUNK>
__global__ void gemv_accum(const float* __restrict__ W,
                           const float* __restrict__ x,
                           float* __restrict__ y, int cols) {
    int c = blockIdx.x;
    int row = blockIdx.y;
    int chunk = cols / NCHUNK;
    const float4* W4 = (const float4*)(W + (size_t)row * cols + (size_t)c * chunk);
    const float4* x4 = (const float4*)(x + c * chunk);
    int n4 = chunk >> 2;
    float s = 0.f;
    for (int j = threadIdx.x; j < n4; j += BLOCK) {
        float4 w = W4[j], xx = x4[j];
        s += w.x * xx.x + w.y * xx.y + w.z * xx.z + w.w * xx.w;
    }
#pragma unroll
    for (int off = 32; off > 0; off >>= 1) s += __shfl_down(s, off, 64);
    __shared__ float red[BLOCK / 64];
    int t = threadIdx.x;
    if ((t & 63) == 0) red[t >> 6] = s;
    __syncthreads();
    if (t == 0) {
        float tot = 0.f;
#pragma unroll
        for (int w = 0; w < BLOCK / 64; ++w) tot += red[w];
        atomicAdd(&y[row], tot);
    }
}

// block-per-row GEMV; optionally applies ReLU to x elements on load.
template <int BLOCK, bool RELUX>
__global__ void gemv_relu(const float* __restrict__ W,
                          const float* __restrict__ x,
                          const float* __restrict__ bias,
                          float* __restrict__ y, int cols) {
    int row = blockIdx.x;
    const float4* W4 = (const float4*)(W + (size_t)row * cols);
    const float4* x4 = (const float4*)x;
    int n4 = cols >> 2;
    float s = 0.f;
    for (int j = threadIdx.x; j < n4; j += BLOCK) {
        float4 w = W4[j], xx = x4[j];
        if (RELUX) {
            xx.x = fmaxf(xx.x, 0.f); xx.y = fmaxf(xx.y, 0.f);
            xx.z = fmaxf(xx.z, 0.f); xx.w = fmaxf(xx.w, 0.f);
        }
        s += w.x * xx.x + w.y * xx.y + w.z * xx.z + w.w * xx.w;
    }
#pragma unroll
    for (int off = 32; off > 0; off >>= 1) s += __shfl_down(s, off, 64);
    __shared__ float red[BLOCK / 64];
    int t = threadIdx.x;
    if ((t & 63) == 0) red[t >> 6] = s;
    __syncthreads();
    if (t == 0) {
        float tot = 0.f;
#pragma unroll
        for (int w = 0; w < BLOCK / 64; ++w) tot += red[w];
        y[row] = fmaxf(tot + bias[row], 0.f);
    }
}

// ======================= fallback (round-1 atomic path) =======================

__global__ void init_ws_fb(unsigned* __restrict__ p, int n) {
    int i = blockIdx.x * blockDim.x + threadIdx.x;
    if (i < n) p[i] = 0u;
}

__global__ void edge_kernel_fb(const int* __restrict__ ei,
                               const float* __restrict__ X,
                               const float* __restrict__ wl,
                               float* __restrict__ sumw,
                               float* __restrict__ cnt,
                               unsigned* __restrict__ maxb) {
    int e = blockIdx.x * blockDim.x + threadIdx.x;
    if (e >= N_EDGES) return;
    int src = ei[e];
    int dst = ei[N_EDGES + e];
    const float4* X4 = (const float4*)(X + src * F_IN);
    float4 a = X4[0], b = X4[1];
    float f[8] = {a.x, a.y, a.z, a.w, b.x, b.y, b.z, b.w};
    float d = 0.f;
#pragma unroll
    for (int k = 0; k < 8; ++k) d += f[k] * wl[k];
    atomicAdd(&sumw[dst], d);
    atomicAdd(&cnt[dst], 1.0f);
    unsigned* mb = maxb + (size_t)dst * 8;
#pragma unroll
    for (int k = 0; k < 8; ++k) atomicMax(&mb[k], fkey(f[k]));
}

__global__ void node_kernel_fb(const float* __restrict__ X,
                               const float* __restrict__ sumw,
                               const float* __restrict__ cnt,
                               const unsigned* __restrict__ maxb,
                               const float* __restrict__ lin_l_b,
                               const float* __restrict__ lin_r_w,
                               const float* __restrict__ lin_l1_w,
                               const float* __restrict__ lin_l1_b,
                               const float* __restrict__ lin_r1_w,
                               float* __restrict__ xout) {
    int i = blockIdx.x * blockDim.x + threadIdx.x;
    if (i >= N_NODES) return;
    float c = cnt[i];
    float mean_dot = sumw[i] / fmaxf(c, 1.0f);
    const float4* X4 = (const float4*)(X + i * F_IN);
    float4 a = X4[0], b = X4[1];
    float f[8] = {a.x, a.y, a.z, a.w, b.x, b.y, b.z, b.w};
    const uint4* M4 = (const uint4*)(maxb + (size_t)i * 8);
    uint4 m0 = M4[0], m1 = M4[1];
    unsigned mk[8] = {m0.x, m0.y, m0.z, m0.w, m1.x, m1.y, m1.z, m1.w};
    float dr = 0.f, dr1 = 0.f, dmax = 0.f;
    bool nonempty = (c > 0.f);
#pragma unroll
    for (int k = 0; k < 8; ++k) {
        float mxv = nonempty ? funkey(mk[k]) : 0.0f;
        dmax += mxv * lin_l1_w[k];
        dr   += f[k] * lin_r_w[k];
        dr1  += f[k] * lin_r1_w[k];
    }
    float hm = fmaxf(mean_dot + lin_l_b[0] + dr, 0.f);
    float hx = fmaxf(dmax + lin_l1_b[0] + dr1, 0.f);
    xout[i] = hm + hx;
}

// ======================= launch =======================

extern "C" void kernel_launch(void* const* d_in, const int* in_sizes, int n_in,
                              void* d_out, int out_size, void* d_ws, size_t ws_size,
                              hipStream_t stream) {
    const float* X        = (const float*)d_in[0];
    const int*   ei       = (const int*)d_in[1];
    const float* lin_l_w  = (const float*)d_in[2];
    const float* lin_l_b  = (const float*)d_in[3];
    const float* lin_r_w  = (const float*)d_in[4];
    const float* lin_l1_w = (const float*)d_in[5];
    const float* lin_l1_b = (const float*)d_in[6];
    const float* lin_r1_w = (const float*)d_in[7];
    const float* W0       = (const float*)d_in[8];
    const float* b0       = (const float*)d_in[9];
    const float* W1       = (const float*)d_in[10];
    const float* b1       = (const float*)d_in[11];
    const float* W2       = (const float*)d_in[12];
    const float* b2       = (const float*)d_in[13];

    float* xemb = (float*)d_out;
    float* out2 = xemb + N_NODES;

    // ws layout (words): zeroed first: [cursor NB][ovf_cnt N][ovf_sum N][ovf_max N*8]
    // then: [binned NB*CAP_B][h0 HID][h1 HID]
    const size_t zero_words = (size_t)NB + (size_t)N_NODES * 10;
    const size_t need_words = zero_words + (size_t)NB * CAP_B + 2 * HID;
    if (ws_size >= need_words * 4) {
        int*      cursor  = (int*)d_ws;                            // [NB]
        int*      ovf_cnt = cursor + NB;                           // [N]
        float*    ovf_sum = (float*)(ovf_cnt + N_NODES);           // [N]
        unsigned* ovf_max = (unsigned*)(ovf_sum + N_NODES);        // [N*8]
        unsigned* binned  = ovf_max + (size_t)N_NODES * 8;         // [NB*CAP_B]
        float*    h0      = (float*)(binned + (size_t)NB * CAP_B); // [HID]
        float*    h1      = h0 + HID;                              // [HID]

        hipLaunchKernelGGL(init_kernel, dim3(((int)zero_words + 255) / 256), dim3(256), 0, stream,
                           (unsigned*)d_ws, (int)zero_words, b0, h0);
        hipLaunchKernelGGL(bin_kernel, dim3(NBIN_BLOCKS), dim3(256), 0, stream,
                           ei, X, lin_l_w, cursor, binned, ovf_cnt, ovf_sum, ovf_max);
        hipLaunchKernelGGL(agg_kernel, dim3(NB), dim3(512), 0, stream,
                           cursor, binned, ovf_cnt, ovf_sum, ovf_max, X,
                           lin_l_w, lin_l_b, lin_r_w, lin_l1_w, lin_l1_b, lin_r1_w, xemb);

        hipLaunchKernelGGL((gemv_accum<256, NCHUNK0>), dim3(NCHUNK0, HID), dim3(256), 0, stream,
                           W0, xemb, h0, N_NODES);
        hipLaunchKernelGGL((gemv_relu<256, true>), dim3(HID), dim3(256), 0, stream,
                           W1, h0, b1, h1, HID);
        hipLaunchKernelGGL((gemv_relu<256, false>), dim3(R_OUT), dim3(256), 0, stream,
                           W2, h1, b2, out2, HID);
    } else {
        float*    sumw = (float*)d_ws;
        float*    cntf = sumw + N_NODES;
        unsigned* maxb = (unsigned*)(cntf + N_NODES);
        float*    h0   = (float*)(maxb + (size_t)N_NODES * 8);
        float*    h1   = h0 + HID;

        int zw = N_NODES * 10;
        hipLaunchKernelGGL(init_ws_fb, dim3((zw + 255) / 256), dim3(256), 0, stream,
                           (unsigned*)d_ws, zw);
        hipLaunchKernelGGL(edge_kernel_fb, dim3((N_EDGES + 255) / 256), dim3(256), 0, stream,
                           ei, X, lin_l_w, sumw, cntf, maxb);
        hipLaunchKernelGGL(node_kernel_fb, dim3((N_NODES + 255) / 256), dim3(256), 0, stream,
                           X, sumw, cntf, maxb, lin_l_b, lin_r_w, lin_l1_w, lin_l1_b,
                           lin_r1_w, xemb);
        // h0 = relu(W0 x + b0) via accum path needs seeded h0; do plain 3-kernel chain
        hipLaunchKernelGGL((gemv_relu<256, false>), dim3(HID), dim3(256), 0, stream,
                           W0, xemb, b0, h0, N_NODES);
        hipLaunchKernelGGL((gemv_relu<256, false>), dim3(HID), dim3(256), 0, stream,
                           W1, h0, b1, h1, HID);
        hipLaunchKernelGGL((gemv_relu<256, false>), dim3(R_OUT), dim3(256), 0, stream,
                           W2, h1, b2, out2, HID);
    }
}